// Round 2
// baseline (330.465 us; speedup 1.0000x reference)
//
#include <hip/hip_runtime.h>

typedef __bf16 bf16;
typedef __bf16 bf16x2 __attribute__((ext_vector_type(2)));
typedef __bf16 bf16x4 __attribute__((ext_vector_type(4)));
typedef __bf16 bf16x8 __attribute__((ext_vector_type(8)));
typedef float f32x4 __attribute__((ext_vector_type(4)));

constexpr int Bsz = 4, S = 2048, H = 512, NH = 8, DH = 64;
constexpr int M = Bsz * S;   // 8192 rows
constexpr int K = H;         // 512 reduction dim
constexpr int WELEM = H * H; // 262144 elems per weight matrix

// ---------------------------------------------------------------------------
// Weight convert: fp32 -> bf16. grid=(256,4): y picks which weight.
// ---------------------------------------------------------------------------
__global__ __launch_bounds__(256) void convert_w(
    const float* __restrict__ w0, const float* __restrict__ w1,
    const float* __restrict__ w2, const float* __restrict__ w3,
    bf16* __restrict__ dst) {
    int y = blockIdx.y;
    const float* src = (y == 0) ? w0 : (y == 1) ? w1 : (y == 2) ? w2 : w3;
    bf16* d = dst + (size_t)y * WELEM;
    int i = (blockIdx.x * 256 + threadIdx.x) * 4;
    float4 v = *(const float4*)(src + i);
    bf16x4 o;
    o.x = (bf16)v.x; o.y = (bf16)v.y; o.z = (bf16)v.z; o.w = (bf16)v.w;
    *(bf16x4*)(d + i) = o;
}

// ---------------------------------------------------------------------------
// LN1: fp32 in -> bf16 out. One block per row, 256 threads x 2 elems.
// ---------------------------------------------------------------------------
__global__ __launch_bounds__(256) void ln_f32_bf16(
    const float* __restrict__ x, const float* __restrict__ g,
    const float* __restrict__ b, bf16* __restrict__ y) {
    int row = blockIdx.x;
    int t = threadIdx.x;
    float2 xv = *(const float2*)(x + (size_t)row * H + t * 2);
    float v0 = xv.x, v1 = xv.y;
    float s = v0 + v1, s2 = v0 * v0 + v1 * v1;
    for (int off = 1; off < 64; off <<= 1) {
        s  += __shfl_xor(s,  off, 64);
        s2 += __shfl_xor(s2, off, 64);
    }
    __shared__ float red[8];
    int wid = t >> 6;
    if ((t & 63) == 0) { red[wid * 2] = s; red[wid * 2 + 1] = s2; }
    __syncthreads();
    s  = red[0] + red[2] + red[4] + red[6];
    s2 = red[1] + red[3] + red[5] + red[7];
    float mu  = s * (1.0f / H);
    float var = s2 * (1.0f / H) - mu * mu;
    float inv = rsqrtf(var + 1e-12f);
    float2 gv = *(const float2*)(g + t * 2);
    float2 bv = *(const float2*)(b + t * 2);
    bf16x2 out;
    out.x = (bf16)((v0 - mu) * inv * gv.x + bv.x);
    out.y = (bf16)((v1 - mu) * inv * gv.y + bv.y);
    *(bf16x2*)(y + (size_t)row * H + t * 2) = out;
}

// LN2: bf16 in -> fp32 out.
__global__ __launch_bounds__(256) void ln_bf16_f32(
    const bf16* __restrict__ x, const float* __restrict__ g,
    const float* __restrict__ b, float* __restrict__ y) {
    int row = blockIdx.x;
    int t = threadIdx.x;
    bf16x2 xv = *(const bf16x2*)(x + (size_t)row * H + t * 2);
    float v0 = (float)xv.x, v1 = (float)xv.y;
    float s = v0 + v1, s2 = v0 * v0 + v1 * v1;
    for (int off = 1; off < 64; off <<= 1) {
        s  += __shfl_xor(s,  off, 64);
        s2 += __shfl_xor(s2, off, 64);
    }
    __shared__ float red[8];
    int wid = t >> 6;
    if ((t & 63) == 0) { red[wid * 2] = s; red[wid * 2 + 1] = s2; }
    __syncthreads();
    s  = red[0] + red[2] + red[4] + red[6];
    s2 = red[1] + red[3] + red[5] + red[7];
    float mu  = s * (1.0f / H);
    float var = s2 * (1.0f / H) - mu * mu;
    float inv = rsqrtf(var + 1e-12f);
    float2 gv = *(const float2*)(g + t * 2);
    float2 bv = *(const float2*)(b + t * 2);
    float2 out;
    out.x = (v0 - mu) * inv * gv.x + bv.x;
    out.y = (v1 - mu) * inv * gv.y + bv.y;
    *(float2*)(y + (size_t)row * H + t * 2) = out;
}

// ---------------------------------------------------------------------------
// Shared GEMM mainloop: C[64x64] tile of A[M,K] @ W[N,K]^T, bf16 inputs.
// Block 256 = 4 waves; each wave does a 32x32 subtile (2x2 MFMA 16x16x32).
// LDS rows padded to 40 elems (80 B) -> only 2-way bank aliasing (free).
// ---------------------------------------------------------------------------
#define LDT 40
__device__ inline void gemm_mainloop(const bf16* __restrict__ A,
                                     const bf16* __restrict__ W,
                                     int bm, int bn, bf16* As, bf16* Ws,
                                     f32x4 acc[2][2]) {
    int t = threadIdx.x;
    int lane = t & 63, wid = t >> 6;
    int quad = lane >> 4, ln16 = lane & 15;
    int wm = wid & 1, wn = wid >> 1;
    int lrow = t >> 2, lcol = (t & 3) * 8;
    for (int kt = 0; kt < K; kt += 32) {
        __syncthreads();
        *(uint4*)&As[lrow * LDT + lcol] =
            *(const uint4*)&A[(size_t)(bm + lrow) * K + kt + lcol];
        *(uint4*)&Ws[lrow * LDT + lcol] =
            *(const uint4*)&W[(size_t)(bn + lrow) * K + kt + lcol];
        __syncthreads();
        bf16x8 af[2], wf[2];
        for (int i = 0; i < 2; i++) {
            af[i] = *(const bf16x8*)&As[(wm * 32 + i * 16 + ln16) * LDT + quad * 8];
            wf[i] = *(const bf16x8*)&Ws[(wn * 32 + i * 16 + ln16) * LDT + quad * 8];
        }
        for (int mi = 0; mi < 2; mi++)
            for (int ni = 0; ni < 2; ni++)
                acc[mi][ni] = __builtin_amdgcn_mfma_f32_16x16x32_bf16(
                    af[mi], wf[ni], acc[mi][ni], 0, 0, 0);
    }
}

// QKV projection. grid = (M/64, H/64, 3); z=0:q, z=1:k (both [B,NH,S,DH]),
// z=2: v stored transposed [B,NH,DH,S] for the PV B-operand.
__global__ __launch_bounds__(256) void gemm_qkv(
    const bf16* __restrict__ h, const bf16* __restrict__ wb,
    const float* __restrict__ bq, const float* __restrict__ bk,
    const float* __restrict__ bv,
    bf16* __restrict__ qd, bf16* __restrict__ kd, bf16* __restrict__ vtd) {
    __shared__ alignas(16) bf16 As[64 * LDT];
    __shared__ alignas(16) bf16 Ws[64 * LDT];
    int bm = blockIdx.x * 64, bn = blockIdx.y * 64, z = blockIdx.z;
    const bf16* W = wb + (size_t)z * WELEM;
    const float* bias = (z == 0) ? bq : (z == 1) ? bk : bv;
    f32x4 acc[2][2];
    for (int mi = 0; mi < 2; mi++)
        for (int ni = 0; ni < 2; ni++)
            for (int r = 0; r < 4; r++) acc[mi][ni][r] = 0.0f;
    gemm_mainloop(h, W, bm, bn, As, Ws, acc);
    int lane = threadIdx.x & 63, wid = threadIdx.x >> 6;
    int quad = lane >> 4, ln16 = lane & 15;
    int wm = wid & 1, wn = wid >> 1;
    for (int mi = 0; mi < 2; mi++)
        for (int ni = 0; ni < 2; ni++)
            for (int r = 0; r < 4; r++) {
                int i = bm + wm * 32 + mi * 16 + quad * 4 + r;
                int j = bn + wn * 32 + ni * 16 + ln16;
                float val = acc[mi][ni][r] + bias[j];
                int b = i >> 11, srow = i & (S - 1);
                int nh = j >> 6, d = j & (DH - 1);
                if (z < 2) {
                    bf16* dst = (z == 0) ? qd : kd;
                    dst[(((size_t)(b * NH + nh)) * S + srow) * DH + d] = (bf16)val;
                } else {
                    vtd[(((size_t)(b * NH + nh)) * DH + d) * S + srow] = (bf16)val;
                }
            }
}

// Output projection + bias + residual(h) -> tmp (bf16, row-major [M,H])
__global__ __launch_bounds__(256) void gemm_out(
    const bf16* __restrict__ ctx, const bf16* __restrict__ wo,
    const float* __restrict__ bo, const bf16* __restrict__ resid,
    bf16* __restrict__ dst) {
    __shared__ alignas(16) bf16 As[64 * LDT];
    __shared__ alignas(16) bf16 Ws[64 * LDT];
    int bm = blockIdx.x * 64, bn = blockIdx.y * 64;
    f32x4 acc[2][2];
    for (int mi = 0; mi < 2; mi++)
        for (int ni = 0; ni < 2; ni++)
            for (int r = 0; r < 4; r++) acc[mi][ni][r] = 0.0f;
    gemm_mainloop(ctx, wo, bm, bn, As, Ws, acc);
    int lane = threadIdx.x & 63, wid = threadIdx.x >> 6;
    int quad = lane >> 4, ln16 = lane & 15;
    int wm = wid & 1, wn = wid >> 1;
    for (int mi = 0; mi < 2; mi++)
        for (int ni = 0; ni < 2; ni++)
            for (int r = 0; r < 4; r++) {
                int i = bm + wm * 32 + mi * 16 + quad * 4 + r;
                int j = bn + wn * 32 + ni * 16 + ln16;
                float val = acc[mi][ni][r] + bo[j]
                          + (float)resid[(size_t)i * H + j];
                dst[(size_t)i * H + j] = (bf16)val;
            }
}

// ---------------------------------------------------------------------------
// Flash attention: grid = (S/64, B*NH). Block 256 = 4 waves, each owns 16 q
// rows. 32-key steps; K/V staged in LDS per block; online softmax; P goes
// through per-wave LDS to convert MFMA C-layout -> A-layout.
// ---------------------------------------------------------------------------
__global__ __launch_bounds__(256) void attn_kernel(
    const bf16* __restrict__ q, const bf16* __restrict__ k,
    const bf16* __restrict__ vt, const float* __restrict__ mask,
    bf16* __restrict__ ctx) {
    int qblk = blockIdx.x * 64;
    int bh = blockIdx.y;                 // b*NH + nh
    int b = bh >> 3, nh = bh & 7;
    int t = threadIdx.x, wid = t >> 6, lane = t & 63;
    int quad = lane >> 4, n = lane & 15;

    const bf16* Q  = q  + (size_t)bh * S * DH;
    const bf16* Kp = k  + (size_t)bh * S * DH;
    const bf16* Vt = vt + (size_t)bh * DH * S;
    const float* mrow = mask + (size_t)b * S;

    __shared__ alignas(16) bf16 Ks[32 * 72];     // [key][dh], rows padded to 72
    __shared__ alignas(16) bf16 Vs[64 * LDT];    // [d][key],  rows padded to 40
    __shared__ alignas(16) bf16 Ps[4][16 * LDT]; // per-wave P tile [qrow][key]

    int qrow = qblk + wid * 16 + n;      // A-frag: m = lane&15
    bf16x8 qf0 = *(const bf16x8*)&Q[(size_t)qrow * DH + quad * 8];
    bf16x8 qf1 = *(const bf16x8*)&Q[(size_t)qrow * DH + 32 + quad * 8];

    f32x4 O[4];
    for (int i = 0; i < 4; i++)
        for (int r = 0; r < 4; r++) O[i][r] = 0.0f;
    float m_run[4], l_run[4];
    for (int r = 0; r < 4; r++) { m_run[r] = -1e30f; l_run[r] = 0.0f; }

    for (int kb = 0; kb < S; kb += 32) {
        __syncthreads();  // protect LDS from previous iteration's readers
        {
            int row = t >> 3, c = (t & 7) * 8;          // K tile 32x64
            *(uint4*)&Ks[row * 72 + c] =
                *(const uint4*)&Kp[(size_t)(kb + row) * DH + c];
            int d = t >> 2, kc = (t & 3) * 8;           // V tile 64x32 (as Vt)
            *(uint4*)&Vs[d * LDT + kc] =
                *(const uint4*)&Vt[(size_t)d * S + kb + kc];
        }
        __syncthreads();
        // scores: two 16x16 tiles (keys kb+n, kb+16+n)
        f32x4 s0, s1;
        for (int r = 0; r < 4; r++) { s0[r] = 0.0f; s1[r] = 0.0f; }
        bf16x8 k0a = *(const bf16x8*)&Ks[n * 72 + quad * 8];
        bf16x8 k0b = *(const bf16x8*)&Ks[n * 72 + 32 + quad * 8];
        bf16x8 k1a = *(const bf16x8*)&Ks[(16 + n) * 72 + quad * 8];
        bf16x8 k1b = *(const bf16x8*)&Ks[(16 + n) * 72 + 32 + quad * 8];
        s0 = __builtin_amdgcn_mfma_f32_16x16x32_bf16(qf0, k0a, s0, 0, 0, 0);
        s0 = __builtin_amdgcn_mfma_f32_16x16x32_bf16(qf1, k0b, s0, 0, 0, 0);
        s1 = __builtin_amdgcn_mfma_f32_16x16x32_bf16(qf0, k1a, s1, 0, 0, 0);
        s1 = __builtin_amdgcn_mfma_f32_16x16x32_bf16(qf1, k1b, s1, 0, 0, 0);

        float mk0 = mrow[kb + n], mk1 = mrow[kb + 16 + n];
        float p0[4], p1[4], alpha[4], mx[4], rs[4];
        for (int r = 0; r < 4; r++) {
            p0[r] = s0[r] * 0.125f + mk0;   // 1/sqrt(64) = 0.125
            p1[r] = s1[r] * 0.125f + mk1;
            mx[r] = fmaxf(p0[r], p1[r]);
        }
        for (int off = 1; off < 16; off <<= 1)
            for (int r = 0; r < 4; r++)
                mx[r] = fmaxf(mx[r], __shfl_xor(mx[r], off, 64));
        for (int r = 0; r < 4; r++) {
            float mn = fmaxf(m_run[r], mx[r]);
            alpha[r] = __expf(m_run[r] - mn);
            p0[r] = __expf(p0[r] - mn);
            p1[r] = __expf(p1[r] - mn);
            rs[r] = p0[r] + p1[r];
            m_run[r] = mn;
        }
        for (int off = 1; off < 16; off <<= 1)
            for (int r = 0; r < 4; r++)
                rs[r] += __shfl_xor(rs[r], off, 64);
        for (int r = 0; r < 4; r++)
            l_run[r] = alpha[r] * l_run[r] + rs[r];

        // P: C-layout (row=quad*4+r, col=n / 16+n) -> per-wave LDS
        bf16* P = Ps[wid];
        for (int r = 0; r < 4; r++) {
            P[(quad * 4 + r) * LDT + n]      = (bf16)p0[r];
            P[(quad * 4 + r) * LDT + 16 + n] = (bf16)p1[r];
        }
        __syncthreads();  // make P visible across lanes
        for (int dt = 0; dt < 4; dt++)
            for (int r = 0; r < 4; r++)
                O[dt][r] *= alpha[r];
        bf16x8 pf = *(const bf16x8*)&P[n * LDT + quad * 8];  // A-layout
        for (int dt = 0; dt < 4; dt++) {
            bf16x8 vf = *(const bf16x8*)&Vs[(dt * 16 + n) * LDT + quad * 8];
            O[dt] = __builtin_amdgcn_mfma_f32_16x16x32_bf16(pf, vf, O[dt], 0, 0, 0);
        }
    }
    // epilogue: ctx[b, s, nh*64 + d] row-major [M, H]
    for (int dt = 0; dt < 4; dt++)
        for (int r = 0; r < 4; r++) {
            int srow = qblk + wid * 16 + quad * 4 + r;
            int col = nh * 64 + dt * 16 + n;
            float val = O[dt][r] / l_run[r];
            ctx[((size_t)(b * S + srow)) * H + col] = (bf16)val;
        }
}

// ---------------------------------------------------------------------------
extern "C" void kernel_launch(void* const* d_in, const int* in_sizes, int n_in,
                              void* d_out, int out_size, void* d_ws, size_t ws_size,
                              hipStream_t stream) {
    const float* hidden = (const float*)d_in[0];
    const float* mask   = (const float*)d_in[1];
    const float* ln1_g  = (const float*)d_in[2];
    const float* ln1_b  = (const float*)d_in[3];
    const float* wq = (const float*)d_in[4],  *bq = (const float*)d_in[5];
    const float* wk = (const float*)d_in[6],  *bk = (const float*)d_in[7];
    const float* wv = (const float*)d_in[8],  *bv = (const float*)d_in[9];
    const float* wo = (const float*)d_in[10], *bo = (const float*)d_in[11];
    const float* ln2_g = (const float*)d_in[12];
    const float* ln2_b = (const float*)d_in[13];

    const size_t T = (size_t)M * H;     // 4M elems per activation tensor
    bf16* wb  = (bf16*)d_ws;            // 4 weights, bf16: 4*WELEM
    bf16* h   = wb  + (size_t)4 * WELEM;
    bf16* qd  = h   + T;
    bf16* kd  = qd  + T;
    bf16* vtd = kd  + T;
    bf16* ctx = vtd + T;
    bf16* tmp = qd;                     // qd is dead after attn_kernel

    convert_w<<<dim3(WELEM / 1024, 4), 256, 0, stream>>>(wq, wk, wv, wo, wb);
    ln_f32_bf16<<<M, 256, 0, stream>>>(hidden, ln1_g, ln1_b, h);
    gemm_qkv<<<dim3(M / 64, H / 64, 3), 256, 0, stream>>>(
        h, wb, bq, bk, bv, qd, kd, vtd);
    attn_kernel<<<dim3(S / 64, Bsz * NH), 256, 0, stream>>>(qd, kd, vtd, mask, ctx);
    gemm_out<<<dim3(M / 64, H / 64), 256, 0, stream>>>(
        ctx, wb + (size_t)3 * WELEM, bo, h, tmp);
    ln_bf16_f32<<<M, 256, 0, stream>>>(tmp, ln2_g, ln2_b, (float*)d_out);
}